// Round 2
// baseline (2920.123 us; speedup 1.0000x reference)
//
#include <hip/hip_runtime.h>
#include <cstdint>

// ---------------------------------------------------------------------------
// QLoRABigNet: 6 blocks x (3 qlora linears + relu/residual) + layernorm.
// Strategy: split-bf16 (hi+lo) MFMA GEMM, 3 products (hh+hl+lh) ~ fp32 acc.
// LoRA fused via K-augmentation: xa=[x|t], Wa=[W|B], K=1024+32 pad-> 1088.
// Per-layer weight pack (1-slot ring, 4.5 MB) keeps ws under ~220 MB.
// ybuf lives in d_out: gemm<1> writes pre-LN sum there; final block's write
// IS the answer.
// GEMM: 128x128 tile, BK=64, 4 waves, global_load_lds(16B), XOR slot swizzle.
// ---------------------------------------------------------------------------

#define NTOK 16384
#define DIM  1024
#define KP   1088     // augmented+padded K (1024 base + 32 lora + 32 zero)
#define RLORA 32
#define NLIN 18
#define NBLK 6

typedef unsigned short u16;
typedef __attribute__((ext_vector_type(8))) short short8;
typedef __attribute__((ext_vector_type(4))) float f32x4;

__device__ __forceinline__ u16 f2bf(float f) {
  uint32_t u = __float_as_uint(f);
  u += 0x7fffu + ((u >> 16) & 1u);          // round-to-nearest-even
  return (u16)(u >> 16);
}
__device__ __forceinline__ float bf2f(u16 h) {
  return __uint_as_float(((uint32_t)h) << 16);
}
__device__ __forceinline__ void split_bf(float f, u16& h, u16& l) {
  h = f2bf(f);
  l = f2bf(f - bf2f(h));                    // exact residual
}

__device__ __forceinline__ void gld16(const void* g, void* lds) {
  __builtin_amdgcn_global_load_lds(
      (const __attribute__((address_space(1))) uint32_t*)g,
      (__attribute__((address_space(3))) uint32_t*)lds, 16, 0, 0);
}

// ---------------------------------------------------------------------------
// Pack kernels (run every launch; ws is re-poisoned each call)
// ---------------------------------------------------------------------------

// One layer: Wa[o][0:1024]=dequant(q,s); [1024:1056]=lora_B[o][:]; rest 0
__global__ void pack_w_k(const int* __restrict__ qw, const float* __restrict__ sc,
                         const float* __restrict__ lb,
                         u16* __restrict__ Wh, u16* __restrict__ Wl) {
  const int idx = blockIdx.x * 256 + threadIdx.x;
  if (idx >= 1024 * (KP / 16)) return;
  const int g = idx % (KP / 16);
  const int o = idx / (KP / 16);
  u16 h[16], l[16];
  if (g < 64) {
    const int* q = qw + (size_t)o * 1024 + g * 16;
    const float s = sc[(size_t)o * 64 + g];
#pragma unroll
    for (int j = 0; j < 16; ++j) {
      float w = ((float)q[j] * (2.0f / 15.0f) - 1.0f) * s;
      split_bf(w, h[j], l[j]);
    }
  } else if (g < 66) {
    const float* B = lb + (size_t)o * RLORA + (g - 64) * 16;
#pragma unroll
    for (int j = 0; j < 16; ++j) split_bf(B[j], h[j], l[j]);
  } else {
#pragma unroll
    for (int j = 0; j < 16; ++j) { h[j] = 0; l[j] = 0; }
  }
  u16* wh = Wh + (size_t)o * KP + g * 16;
  u16* wl = Wl + (size_t)o * KP + g * 16;
#pragma unroll
  for (int j = 0; j < 16; ++j) { wh[j] = h[j]; wl[j] = l[j]; }
}

// Aa[li][r][0:1024]=lora_A; rest 0  (all 18 layers, 2.5 MB)
__global__ void pack_a_k(const float* __restrict__ la,
                         u16* __restrict__ Ah, u16* __restrict__ Al) {
  const int idx = blockIdx.x * 256 + threadIdx.x;
  if (idx >= NLIN * RLORA * (KP / 16)) return;
  const int g = idx % (KP / 16);
  const int rem = idx / (KP / 16);
  const int r = rem % RLORA, li = rem / RLORA;
  u16 h[16], l[16];
  if (g < 64) {
    const float* a = la + ((size_t)li * RLORA + r) * 1024 + g * 16;
#pragma unroll
    for (int j = 0; j < 16; ++j) split_bf(a[j], h[j], l[j]);
  } else {
#pragma unroll
    for (int j = 0; j < 16; ++j) { h[j] = 0; l[j] = 0; }
  }
  u16* ph = Ah + ((size_t)li * RLORA + r) * KP + g * 16;
  u16* pl = Al + ((size_t)li * RLORA + r) * KP + g * 16;
#pragma unroll
  for (int j = 0; j < 16; ++j) { ph[j] = h[j]; pl[j] = l[j]; }
}

// actA[0:1024] = split(x); pad cols (>=1024) of BOTH act buffers zeroed.
__global__ void pack_x_k(const float* __restrict__ x,
                         u16* __restrict__ aAh, u16* __restrict__ aAl,
                         u16* __restrict__ aBh, u16* __restrict__ aBl) {
  const int idx = blockIdx.x * 256 + threadIdx.x;
  if (idx >= NTOK * (KP / 16)) return;
  const int g = idx % (KP / 16);
  const int n = idx / (KP / 16);
  const size_t dofs = (size_t)n * KP + g * 16;
  if (g < 64) {
    const float* xp = x + (size_t)n * DIM + g * 16;
#pragma unroll
    for (int j = 0; j < 16; ++j) {
      u16 h, l;
      split_bf(xp[j], h, l);
      aAh[dofs + j] = h; aAl[dofs + j] = l;
    }
  } else {
#pragma unroll
    for (int j = 0; j < 16; ++j) {
      aAh[dofs + j] = 0; aAl[dofs + j] = 0;
      aBh[dofs + j] = 0; aBl[dofs + j] = 0;
    }
  }
}

// ---------------------------------------------------------------------------
// t kernel: t = act[:,0:1024] @ A^T  (split-bf16, 3-product) -> cols 1024:1056
// 128 rows/block, wave w owns rows [w*32, w*32+32), 2x2 16x16 frags.
// ---------------------------------------------------------------------------
__global__ __launch_bounds__(256, 4) void t_k(
    u16* __restrict__ Xh, u16* __restrict__ Xl,
    const u16* __restrict__ LAh, const u16* __restrict__ LAl) {
  __shared__ __align__(16) u16 sXh[128 * 64], sXl[128 * 64];
  const int tid = threadIdx.x;
  const int lane = tid & 63, wave = tid >> 6;
  const int row0 = blockIdx.x * 128;

  f32x4 acc[2][2];
#pragma unroll
  for (int i = 0; i < 2; ++i)
#pragma unroll
    for (int j = 0; j < 2; ++j) acc[i][j] = {0.f, 0.f, 0.f, 0.f};

  const int sr = tid >> 3;
  const int ss = ((tid & 7) ^ (sr & 7)) * 8;      // swizzled source slot
  const size_t xoff = (size_t)(row0 + sr) * KP + ss;
  const int arow = wave * 32 + (lane & 15);
  const int sl = lane >> 4, sx = lane & 7;

  for (int ks = 0; ks < 16; ++ks) {               // K = 1024 only
    const int kofs = ks * 64;
#pragma unroll
    for (int r = 0; r < 4; ++r) {
      const size_t go = (size_t)(r * 32) * KP + kofs;
      const int lo = wave * 512 + r * 2048;
      gld16(Xh + xoff + go, &sXh[lo]);
      gld16(Xl + xoff + go, &sXl[lo]);
    }
    __syncthreads();
#pragma unroll
    for (int kk = 0; kk < 2; ++kk) {
      const int so = ((kk * 4 + sl) ^ sx) * 8;
      const int o0 = arow * 64 + so;
      const int o1 = (arow + 16) * 64 + so;
      short8 a0h = *(const short8*)&sXh[o0];
      short8 a0l = *(const short8*)&sXl[o0];
      short8 a1h = *(const short8*)&sXh[o1];
      short8 a1l = *(const short8*)&sXl[o1];
#pragma unroll
      for (int ni = 0; ni < 2; ++ni) {
        const int ar = ni * 16 + (lane & 15);
        const int ac = kofs + kk * 32 + sl * 8;
        short8 bh = *(const short8*)&LAh[(size_t)ar * KP + ac];
        short8 bl = *(const short8*)&LAl[(size_t)ar * KP + ac];
        f32x4 c = acc[0][ni];
        c = __builtin_amdgcn_mfma_f32_16x16x32_bf16(a0h, bl, c, 0, 0, 0);
        c = __builtin_amdgcn_mfma_f32_16x16x32_bf16(a0l, bh, c, 0, 0, 0);
        c = __builtin_amdgcn_mfma_f32_16x16x32_bf16(a0h, bh, c, 0, 0, 0);
        acc[0][ni] = c;
        c = acc[1][ni];
        c = __builtin_amdgcn_mfma_f32_16x16x32_bf16(a1h, bl, c, 0, 0, 0);
        c = __builtin_amdgcn_mfma_f32_16x16x32_bf16(a1l, bh, c, 0, 0, 0);
        c = __builtin_amdgcn_mfma_f32_16x16x32_bf16(a1h, bh, c, 0, 0, 0);
        acc[1][ni] = c;
      }
    }
    __syncthreads();
  }
  // write t (split) into augmented cols [1024, 1056)
  const int crow0 = row0 + wave * 32 + (lane >> 4) * 4;
#pragma unroll
  for (int ni = 0; ni < 2; ++ni) {
    const int col = DIM + ni * 16 + (lane & 15);
#pragma unroll
    for (int mi = 0; mi < 2; ++mi)
#pragma unroll
      for (int r = 0; r < 4; ++r) {
        const int rw = crow0 + mi * 16 + r;
        u16 h, l;
        split_bf(acc[mi][ni][r], h, l);
        Xh[(size_t)rw * KP + col] = h;
        Xl[(size_t)rw * KP + col] = l;
      }
  }
}

// ---------------------------------------------------------------------------
// Main GEMM: out[16384,1024] = xa @ Wa^T (+bias, +relu | +resid)
// MODE 0: relu -> split-bf16 act out (stride KP)
// MODE 1: + resid -> fp32 out (stride DIM)
// ---------------------------------------------------------------------------
template <int MODE>
__global__ __launch_bounds__(256, 2) void gemm_k(
    const u16* __restrict__ Xh, const u16* __restrict__ Xl,
    const u16* __restrict__ Wh, const u16* __restrict__ Wl,
    const float* __restrict__ bias, const float* __restrict__ resid,
    float* __restrict__ outf, u16* __restrict__ Oh, u16* __restrict__ Ol) {
  __shared__ __align__(16) u16 sXh[128 * 64], sXl[128 * 64];
  __shared__ __align__(16) u16 sWh[128 * 64], sWl[128 * 64];
  const int tid = threadIdx.x;
  const int lane = tid & 63, wave = tid >> 6;
  const int wr = wave >> 1, wc = wave & 1;
  const int row0 = blockIdx.x * 128, col0 = blockIdx.y * 128;

  f32x4 acc[4][4];
#pragma unroll
  for (int i = 0; i < 4; ++i)
#pragma unroll
    for (int j = 0; j < 4; ++j) acc[i][j] = {0.f, 0.f, 0.f, 0.f};

  // staging: round r covers tile rows [r*32, r*32+32); thread -> row tid/8,
  // source col-slot XOR-swizzled by row&7 so swizzled ds_read is conflict-free.
  const int sr = tid >> 3;
  const int ss = ((tid & 7) ^ (sr & 7)) * 8;
  const size_t xoff = (size_t)(row0 + sr) * KP + ss;
  const size_t woff = (size_t)(col0 + sr) * KP + ss;

  const int arow = wr * 64 + (lane & 15);
  const int brow = wc * 64 + (lane & 15);
  const int sl = lane >> 4, sx = lane & 7;

  for (int ks = 0; ks < KP / 64; ++ks) {
    const int kofs = ks * 64;
#pragma unroll
    for (int r = 0; r < 4; ++r) {
      const size_t go = (size_t)(r * 32) * KP + kofs;
      const int lo = wave * 512 + r * 2048;   // wave-uniform LDS chunk base
      gld16(Xh + xoff + go, &sXh[lo]);
      gld16(Xl + xoff + go, &sXl[lo]);
      gld16(Wh + woff + go, &sWh[lo]);
      gld16(Wl + woff + go, &sWl[lo]);
    }
    __syncthreads();                           // drains vmcnt before barrier
#pragma unroll
    for (int kk = 0; kk < 2; ++kk) {
      const int so = ((kk * 4 + sl) ^ sx) * 8; // swizzled read slot
      short8 ah[4], am[4], bh[4], bm[4];
#pragma unroll
      for (int mi = 0; mi < 4; ++mi) {
        const int off = (arow + mi * 16) * 64 + so;
        ah[mi] = *(const short8*)&sXh[off];
        am[mi] = *(const short8*)&sXl[off];
      }
#pragma unroll
      for (int ni = 0; ni < 4; ++ni) {
        const int off = (brow + ni * 16) * 64 + so;
        bh[ni] = *(const short8*)&sWh[off];
        bm[ni] = *(const short8*)&sWl[off];
      }
#pragma unroll
      for (int mi = 0; mi < 4; ++mi)
#pragma unroll
        for (int ni = 0; ni < 4; ++ni) {
          f32x4 c = acc[mi][ni];
          c = __builtin_amdgcn_mfma_f32_16x16x32_bf16(ah[mi], bm[ni], c, 0, 0, 0);
          c = __builtin_amdgcn_mfma_f32_16x16x32_bf16(am[mi], bh[ni], c, 0, 0, 0);
          c = __builtin_amdgcn_mfma_f32_16x16x32_bf16(ah[mi], bh[ni], c, 0, 0, 0);
          acc[mi][ni] = c;
        }
    }
    __syncthreads();
  }

  // epilogue (C/D: col = lane&15, row = (lane>>4)*4 + reg  [m89/m91])
  const int crow0 = row0 + wr * 64 + (lane >> 4) * 4;
  const int ccol0 = col0 + wc * 64 + (lane & 15);
#pragma unroll
  for (int ni = 0; ni < 4; ++ni) {
    const int col = ccol0 + ni * 16;
    const float bv = bias[col];
#pragma unroll
    for (int mi = 0; mi < 4; ++mi) {
#pragma unroll
      for (int r = 0; r < 4; ++r) {
        const int rw = crow0 + mi * 16 + r;
        float v = acc[mi][ni][r] + bv;
        if (MODE == 0) {
          v = fmaxf(v, 0.f);
          u16 h, l;
          split_bf(v, h, l);
          Oh[(size_t)rw * KP + col] = h;
          Ol[(size_t)rw * KP + col] = l;
        } else {
          v += resid[(size_t)rw * DIM + col];
          outf[(size_t)rw * DIM + col] = v;
        }
      }
    }
  }
}

// ---------------------------------------------------------------------------
// LayerNorm (one row per block) -> fp32 resid buffer + split-bf16 act out
// ---------------------------------------------------------------------------
__global__ __launch_bounds__(256) void ln_k(
    const float* __restrict__ y, const float* __restrict__ g,
    const float* __restrict__ b, float* __restrict__ ro,
    u16* __restrict__ Oh, u16* __restrict__ Ol) {
  const int row = blockIdx.x, tid = threadIdx.x;
  const int lane = tid & 63, wave = tid >> 6;
  __shared__ float r1[4], r2[4];
  const float4 v = ((const float4*)(y + (size_t)row * DIM))[tid];
  float s = v.x + v.y + v.z + v.w;
#pragma unroll
  for (int o = 32; o > 0; o >>= 1) s += __shfl_down(s, o);
  if (lane == 0) r1[wave] = s;
  __syncthreads();
  const float mean = (r1[0] + r1[1] + r1[2] + r1[3]) * (1.0f / DIM);
  const float d0 = v.x - mean, d1 = v.y - mean, d2 = v.z - mean, d3 = v.w - mean;
  float q = d0 * d0 + d1 * d1 + d2 * d2 + d3 * d3;
#pragma unroll
  for (int o = 32; o > 0; o >>= 1) q += __shfl_down(q, o);
  if (lane == 0) r2[wave] = q;
  __syncthreads();
  const float var = (r2[0] + r2[1] + r2[2] + r2[3]) * (1.0f / DIM);
  const float rs = rsqrtf(var + 1e-5f);
  const float4 gv = ((const float4*)g)[tid];
  const float4 bv = ((const float4*)b)[tid];
  const float o0 = d0 * rs * gv.x + bv.x;
  const float o1 = d1 * rs * gv.y + bv.y;
  const float o2 = d2 * rs * gv.z + bv.z;
  const float o3 = d3 * rs * gv.w + bv.w;
  ((float4*)(ro + (size_t)row * DIM))[tid] = make_float4(o0, o1, o2, o3);
  u16 h0, l0, h1, l1, h2, l2, h3, l3;
  split_bf(o0, h0, l0); split_bf(o1, h1, l1);
  split_bf(o2, h2, l2); split_bf(o3, h3, l3);
  ushort4 hh; hh.x = h0; hh.y = h1; hh.z = h2; hh.w = h3;
  ushort4 ll; ll.x = l0; ll.y = l1; ll.z = l2; ll.w = l3;
  *(ushort4*)&Oh[(size_t)row * KP + tid * 4] = hh;
  *(ushort4*)&Ol[(size_t)row * KP + tid * 4] = ll;
}

// ---------------------------------------------------------------------------
extern "C" void kernel_launch(void* const* d_in, const int* in_sizes, int n_in,
                              void* d_out, int out_size, void* d_ws, size_t ws_size,
                              hipStream_t stream) {
  const float* x      = (const float*)d_in[0];
  const int*   qw     = (const int*)d_in[1];
  const float* scales = (const float*)d_in[2];
  const float* bias   = (const float*)d_in[3];
  const float* lora_A = (const float*)d_in[4];
  const float* lora_B = (const float*)d_in[5];
  const float* ln_g   = (const float*)d_in[6];
  const float* ln_b   = (const float*)d_in[7];

  char* p = (char*)d_ws;
  auto carve = [&](size_t bytes) {
    char* r = p;
    p += (bytes + 255) & ~(size_t)255;
    return (void*)r;
  };
  // ws budget (~217 MB): W slot 4.5 + A 2.5 + acts 142.6 + residb 67.1
  u16* Wh  = (u16*)carve((size_t)1024 * KP * 2);       // one layer (ring of 1)
  u16* Wl  = (u16*)carve((size_t)1024 * KP * 2);
  u16* Ah  = (u16*)carve((size_t)NLIN * RLORA * KP * 2);
  u16* Al  = (u16*)carve((size_t)NLIN * RLORA * KP * 2);
  u16* aAh = (u16*)carve((size_t)NTOK * KP * 2);
  u16* aAl = (u16*)carve((size_t)NTOK * KP * 2);
  u16* aBh = (u16*)carve((size_t)NTOK * KP * 2);
  u16* aBl = (u16*)carve((size_t)NTOK * KP * 2);
  float* residb = (float*)carve((size_t)NTOK * DIM * 4);
  float* ybuf   = (float*)d_out;                       // pre-LN sum lives in d_out

  {
    const int tot = NLIN * RLORA * (KP / 16);
    pack_a_k<<<(tot + 255) / 256, 256, 0, stream>>>(lora_A, Ah, Al);
  }
  {
    const int tot = NTOK * (KP / 16);
    pack_x_k<<<(tot + 255) / 256, 256, 0, stream>>>(x, aAh, aAl, aBh, aBl);
  }

  u16 *inH = aAh, *inL = aAl, *outH = aBh, *outL = aBl;
  const float* resid = x;
  const int wtot = 1024 * (KP / 16);
  for (int blk = 0; blk < NBLK; ++blk) {
    for (int j = 0; j < 3; ++j) {
      const int li = 3 * blk + j;
      pack_w_k<<<(wtot + 255) / 256, 256, 0, stream>>>(
          qw + (size_t)li * DIM * DIM, scales + (size_t)li * DIM * (DIM / 16),
          lora_B + (size_t)li * DIM * RLORA, Wh, Wl);
      t_k<<<NTOK / 128, 256, 0, stream>>>(
          inH, inL, Ah + (size_t)li * RLORA * KP, Al + (size_t)li * RLORA * KP);
      const float* lb = bias + (size_t)li * DIM;
      dim3 grid(NTOK / 128, DIM / 128);
      if (j < 2) {
        gemm_k<0><<<grid, 256, 0, stream>>>(inH, inL, Wh, Wl, lb,
                                            nullptr, nullptr, outH, outL);
        u16* t;
        t = inH; inH = outH; outH = t;
        t = inL; inL = outL; outL = t;
      } else {
        gemm_k<1><<<grid, 256, 0, stream>>>(inH, inL, Wh, Wl, lb,
                                            resid, ybuf, nullptr, nullptr);
        if (blk < NBLK - 1) {
          ln_k<<<NTOK, 256, 0, stream>>>(ybuf, ln_g + (size_t)blk * DIM,
                                         ln_b + (size_t)blk * DIM, residb,
                                         outH, outL);
          resid = residb;
          u16* t;
          t = inH; inH = outH; outH = t;
          t = inL; inL = outL; outL = t;
        }
      }
    }
  }
  (void)in_sizes; (void)n_in; (void)out_size; (void)ws_size;
}